// Round 8
// baseline (151.302 us; speedup 1.0000x reference)
//
#include <hip/hip_runtime.h>
#include <hip/hip_fp16.h>

// Trilinear feature interpolation on a regular 65^3 vertex grid.
// R=64, SCALE=1.05, C=64, N=500000.
//
// R8 pipeline (all on `stream`):
//   memset : zero 32768-bin histogram (128 KB)
//   K1     : feats f32->f16 convert (streaming) + point histogram into
//            32768 FINE bins (2x2x2 cells each). Contention: 500k atomics /
//            32k bins = ~15 per address (measured-safe in R6).
//   K2     : ONE-block scan: 1024 threads x 32 contiguous ints each (fixes
//            R6's 15-20us strided single-block scan), Hillis-Steele over
//            1024 partials in LDS.
//   K3     : scatter 16B records {x,y,z,orig} via per-bin cursor atomics
//   K4     : trilerp gather in bin-sorted order + bijective XCD-chunk
//            swizzle. Fine bins make consecutive records share cells/rows:
//            a block's 32 points span ~2 bins (~7KB) -> L1/L2 hits, and
//            ~3 effective cache-line requests per point instead of 8
//            (the measured serve-rate bottleneck across R4/R6/R7).

#define GRID_R     64
#define GRID_R1    65
#define NCHAN      64
#define NVERT      (GRID_R1 * GRID_R1 * GRID_R1)    // 274625
#define FEAT_ELEMS ((size_t)NVERT * NCHAN)          // 17,576,000 floats
#define NBIN2      32768                            // 32^3 bins (2-cell cube)

typedef float    f32x4 __attribute__((ext_vector_type(4)));
typedef _Float16 f16x8 __attribute__((ext_vector_type(8)));

__device__ __forceinline__ void cell_of(float px, float py, float pz,
                                        int& ci, int& cj, int& ck) {
    float x = (px / 2.1f + 0.5f) * 64.0f;
    float y = (py / 2.1f + 0.5f) * 64.0f;
    float z = (pz / 2.1f + 0.5f) * 64.0f;
    x = fminf(fmaxf(x, 0.0f), 64.0f);
    y = fminf(fmaxf(y, 0.0f), 64.0f);
    z = fminf(fmaxf(z, 0.0f), 64.0f);
    ci = min((int)x, GRID_R - 1);
    cj = min((int)y, GRID_R - 1);
    ck = min((int)z, GRID_R - 1);
}

__device__ __forceinline__ int bin_of(int ci, int cj, int ck) {
    return ((ci >> 1) << 10) | ((cj >> 1) << 5) | (ck >> 1);
}

// ---- K1: feats f32->f16 (streaming) + fine-bin point histogram ----
__global__ __launch_bounds__(256) void convert_hist_kernel(
    const f32x4* __restrict__ in,
    f16x8* __restrict__ outF,
    const float* __restrict__ pos,
    int* __restrict__ hist,          // [NBIN2]
    int n8, int n)
{
    int i = blockIdx.x * 256 + threadIdx.x;
    if (i < n8) {
        f32x4 a = __builtin_nontemporal_load(&in[2 * i]);
        f32x4 b = __builtin_nontemporal_load(&in[2 * i + 1]);
        f16x8 h;
        h[0] = (_Float16)a.x; h[1] = (_Float16)a.y;
        h[2] = (_Float16)a.z; h[3] = (_Float16)a.w;
        h[4] = (_Float16)b.x; h[5] = (_Float16)b.y;
        h[6] = (_Float16)b.z; h[7] = (_Float16)b.w;
        __builtin_nontemporal_store(h, &outF[i]);
    }
    if (i < n) {
        int ci, cj, ck;
        cell_of(pos[i * 3], pos[i * 3 + 1], pos[i * 3 + 2], ci, cj, ck);
        atomicAdd(&hist[bin_of(ci, cj, ck)], 1);
    }
}

// ---- K2: one-block exclusive scan of 32768 bins ----
__global__ __launch_bounds__(1024) void scan_kernel(
    const int* __restrict__ hist,    // [NBIN2]
    int* __restrict__ cursor)        // [NBIN2]
{
    __shared__ int s[1024];
    const int t = threadIdx.x;       // each thread owns 32 contiguous bins
    int pre[32];
    int tot = 0;
#pragma unroll
    for (int i = 0; i < 32; ++i) { pre[i] = tot; tot += hist[t * 32 + i]; }
    s[t] = tot;
    __syncthreads();
    for (int off = 1; off < 1024; off <<= 1) {
        int v = (t >= off) ? s[t - off] : 0;
        __syncthreads();
        s[t] += v;
        __syncthreads();
    }
    const int base = s[t] - tot;     // exclusive over the 1024 chunks
#pragma unroll
    for (int i = 0; i < 32; ++i) cursor[t * 32 + i] = base + pre[i];
}

// ---- K3: scatter sorted point records {px,py,pz,orig_idx} ----
__global__ __launch_bounds__(256) void scatter_kernel(
    const float* __restrict__ pos,
    int* __restrict__ cursor,        // [NBIN2]
    f32x4* __restrict__ records,
    int n)
{
    int i = blockIdx.x * 256 + threadIdx.x;
    if (i >= n) return;
    float px = pos[i * 3], py = pos[i * 3 + 1], pz = pos[i * 3 + 2];
    int ci, cj, ck;
    cell_of(px, py, pz, ci, cj, ck);
    int slot = atomicAdd(&cursor[bin_of(ci, cj, ck)], 1);
    f32x4 r = {px, py, pz, __int_as_float(i)};
    __builtin_nontemporal_store(r, &records[slot]);
}

// ---- K4: bin-sorted trilerp gather (fp16 table), XCD-chunked swizzle ----
__global__ __launch_bounds__(256) void trilerp_sorted_kernel(
    const f32x4* __restrict__ records,
    const f16x8* __restrict__ feats,
    f32x4* __restrict__ out4,
    int n, int nwg)
{
    const int o  = blockIdx.x;
    const int x  = o & 7, oo = o >> 3;
    const int q  = nwg >> 3, r = nwg & 7;
    const int vb = (x < r ? x * (q + 1) : r * (q + 1) + (x - r) * q) + oo;

    const int slot = vb * 32 + (threadIdx.x >> 3);  // 8 lanes per point
    if (slot >= n) return;
    const int sub = threadIdx.x & 7;

    const f32x4 rec = records[slot];
    const float px = rec.x, py = rec.y, pz = rec.z;
    const int orig = __float_as_int(rec.w);

    int ci, cj, ck;
    cell_of(px, py, pz, ci, cj, ck);

    const float INV_GS = 64.0f / 2.1f;
    float vx0 = ((float)ci       * 0.015625f - 0.5f) * 2.1f;
    float vx1 = ((float)(ci + 1) * 0.015625f - 0.5f) * 2.1f;
    float vy0 = ((float)cj       * 0.015625f - 0.5f) * 2.1f;
    float vy1 = ((float)(cj + 1) * 0.015625f - 0.5f) * 2.1f;
    float vz0 = ((float)ck       * 0.015625f - 0.5f) * 2.1f;
    float vz1 = ((float)(ck + 1) * 0.015625f - 0.5f) * 2.1f;

    // Corner (dx,dy,dz) weighted by distance to the OPPOSITE vertex.
    float wx1 = fabsf(px - vx0) * INV_GS;
    float wx0 = fabsf(px - vx1) * INV_GS;
    float wy1 = fabsf(py - vy0) * INV_GS;
    float wy0 = fabsf(py - vy1) * INV_GS;
    float wz1 = fabsf(pz - vz0) * INV_GS;
    float wz0 = fabsf(pz - vz1) * INV_GS;

    const int RS = NCHAN / 8;
    const int SY = GRID_R1 * RS;
    const int SX = GRID_R1 * GRID_R1 * RS;
    int base = ((ci * GRID_R1 + cj) * GRID_R1 + ck) * RS + sub;

    f16x8 f000 = feats[base];
    f16x8 f001 = feats[base + RS];
    f16x8 f010 = feats[base + SY];
    f16x8 f011 = feats[base + SY + RS];
    f16x8 f100 = feats[base + SX];
    f16x8 f101 = feats[base + SX + RS];
    f16x8 f110 = feats[base + SX + SY];
    f16x8 f111 = feats[base + SX + SY + RS];

    float w000 = wx0 * wy0 * wz0, w001 = wx0 * wy0 * wz1;
    float w010 = wx0 * wy1 * wz0, w011 = wx0 * wy1 * wz1;
    float w100 = wx1 * wy0 * wz0, w101 = wx1 * wy0 * wz1;
    float w110 = wx1 * wy1 * wz0, w111 = wx1 * wy1 * wz1;

    f32x4 acc0 = {0.f, 0.f, 0.f, 0.f};
    f32x4 acc1 = {0.f, 0.f, 0.f, 0.f};
#define ACCUM(F, W)                                                  \
    { acc0.x += (float)F[0] * W; acc0.y += (float)F[1] * W;          \
      acc0.z += (float)F[2] * W; acc0.w += (float)F[3] * W;          \
      acc1.x += (float)F[4] * W; acc1.y += (float)F[5] * W;          \
      acc1.z += (float)F[6] * W; acc1.w += (float)F[7] * W; }
    ACCUM(f000, w000) ACCUM(f001, w001) ACCUM(f010, w010) ACCUM(f011, w011)
    ACCUM(f100, w100) ACCUM(f101, w101) ACCUM(f110, w110) ACCUM(f111, w111)
#undef ACCUM

    __builtin_nontemporal_store(acc0, &out4[orig * 16 + sub * 2]);
    __builtin_nontemporal_store(acc1, &out4[orig * 16 + sub * 2 + 1]);
}

// ---- fallback: unsorted fp16 gather (medium ws) ----
__global__ __launch_bounds__(256) void trilerp_f16_kernel(
    const float* __restrict__ pos,
    const f16x8* __restrict__ feats,
    f32x4* __restrict__ out4,
    int n)
{
    const int tid = blockIdx.x * 256 + threadIdx.x;
    const int pt  = tid >> 3;
    if (pt >= n) return;
    const int sub = tid & 7;

    const float px = pos[pt * 3], py = pos[pt * 3 + 1], pz = pos[pt * 3 + 2];
    int ci, cj, ck;
    cell_of(px, py, pz, ci, cj, ck);

    const float INV_GS = 64.0f / 2.1f;
    float vx0 = ((float)ci       * 0.015625f - 0.5f) * 2.1f;
    float vx1 = ((float)(ci + 1) * 0.015625f - 0.5f) * 2.1f;
    float vy0 = ((float)cj       * 0.015625f - 0.5f) * 2.1f;
    float vy1 = ((float)(cj + 1) * 0.015625f - 0.5f) * 2.1f;
    float vz0 = ((float)ck       * 0.015625f - 0.5f) * 2.1f;
    float vz1 = ((float)(ck + 1) * 0.015625f - 0.5f) * 2.1f;

    float wx1 = fabsf(px - vx0) * INV_GS;
    float wx0 = fabsf(px - vx1) * INV_GS;
    float wy1 = fabsf(py - vy0) * INV_GS;
    float wy0 = fabsf(py - vy1) * INV_GS;
    float wz1 = fabsf(pz - vz0) * INV_GS;
    float wz0 = fabsf(pz - vz1) * INV_GS;

    const int RS = NCHAN / 8, SY = GRID_R1 * RS, SX = GRID_R1 * GRID_R1 * RS;
    int base = ((ci * GRID_R1 + cj) * GRID_R1 + ck) * RS + sub;

    f16x8 f000 = feats[base];
    f16x8 f001 = feats[base + RS];
    f16x8 f010 = feats[base + SY];
    f16x8 f011 = feats[base + SY + RS];
    f16x8 f100 = feats[base + SX];
    f16x8 f101 = feats[base + SX + RS];
    f16x8 f110 = feats[base + SX + SY];
    f16x8 f111 = feats[base + SX + SY + RS];

    float w000 = wx0 * wy0 * wz0, w001 = wx0 * wy0 * wz1;
    float w010 = wx0 * wy1 * wz0, w011 = wx0 * wy1 * wz1;
    float w100 = wx1 * wy0 * wz0, w101 = wx1 * wy0 * wz1;
    float w110 = wx1 * wy1 * wz0, w111 = wx1 * wy1 * wz1;

    f32x4 acc0 = {0.f, 0.f, 0.f, 0.f};
    f32x4 acc1 = {0.f, 0.f, 0.f, 0.f};
#define ACCUM(F, W)                                                  \
    { acc0.x += (float)F[0] * W; acc0.y += (float)F[1] * W;          \
      acc0.z += (float)F[2] * W; acc0.w += (float)F[3] * W;          \
      acc1.x += (float)F[4] * W; acc1.y += (float)F[5] * W;          \
      acc1.z += (float)F[6] * W; acc1.w += (float)F[7] * W; }
    ACCUM(f000, w000) ACCUM(f001, w001) ACCUM(f010, w010) ACCUM(f011, w011)
    ACCUM(f100, w100) ACCUM(f101, w101) ACCUM(f110, w110) ACCUM(f111, w111)
#undef ACCUM

    __builtin_nontemporal_store(acc0, &out4[pt * 16 + sub * 2]);
    __builtin_nontemporal_store(acc1, &out4[pt * 16 + sub * 2 + 1]);
}

// ---- fallback: direct f32 gather (tiny ws) ----
__global__ __launch_bounds__(256) void trilerp_f32_kernel(
    const float* __restrict__ pos,
    const f32x4* __restrict__ feats4,
    f32x4* __restrict__ out4,
    int n)
{
    const int tid = blockIdx.x * 256 + threadIdx.x;
    const int pt  = tid >> 4;
    if (pt >= n) return;
    const int sub = tid & 15;

    const float px = pos[pt * 3], py = pos[pt * 3 + 1], pz = pos[pt * 3 + 2];
    int ci, cj, ck;
    cell_of(px, py, pz, ci, cj, ck);

    const float INV_GS = 64.0f / 2.1f;
    float vx0 = ((float)ci       * 0.015625f - 0.5f) * 2.1f;
    float vx1 = ((float)(ci + 1) * 0.015625f - 0.5f) * 2.1f;
    float vy0 = ((float)cj       * 0.015625f - 0.5f) * 2.1f;
    float vy1 = ((float)(cj + 1) * 0.015625f - 0.5f) * 2.1f;
    float vz0 = ((float)ck       * 0.015625f - 0.5f) * 2.1f;
    float vz1 = ((float)(ck + 1) * 0.015625f - 0.5f) * 2.1f;

    float wx1 = fabsf(px - vx0) * INV_GS, wx0 = fabsf(px - vx1) * INV_GS;
    float wy1 = fabsf(py - vy0) * INV_GS, wy0 = fabsf(py - vy1) * INV_GS;
    float wz1 = fabsf(pz - vz0) * INV_GS, wz0 = fabsf(pz - vz1) * INV_GS;
    float w[8] = {wx0*wy0*wz0, wx0*wy0*wz1, wx0*wy1*wz0, wx0*wy1*wz1,
                  wx1*wy0*wz0, wx1*wy0*wz1, wx1*wy1*wz0, wx1*wy1*wz1};

    const int RS = 16, SY = GRID_R1 * RS, SX = GRID_R1 * GRID_R1 * RS;
    const int off[8] = {0, RS, SY, SY + RS, SX, SX + RS, SX + SY, SX + SY + RS};
    int b = ((ci * GRID_R1 + cj) * GRID_R1 + ck) * 16 + sub;

    f32x4 acc = {0.f, 0.f, 0.f, 0.f};
#pragma unroll
    for (int c = 0; c < 8; ++c) acc += feats4[b + off[c]] * w[c];

    __builtin_nontemporal_store(acc, &out4[pt * 16 + sub]);
}

extern "C" void kernel_launch(void* const* d_in, const int* in_sizes, int n_in,
                              void* d_out, int out_size, void* d_ws, size_t ws_size,
                              hipStream_t stream) {
    const float* pos   = (const float*)d_in[0];
    const float* feats = (const float*)d_in[1];
    // d_in[2] (vertices) and d_in[3] (grid_indices) recomputed analytically.
    f32x4* out4 = (f32x4*)d_out;

    const int n  = in_sizes[0] / 3;                 // 500000
    const int n8 = (int)(FEAT_ELEMS / 8);           // 2,197,000

    const size_t featBytes = FEAT_ELEMS * sizeof(_Float16);      // 35.15 MB
    const size_t offF = 0;
    const size_t offR = (featBytes + 127) & ~(size_t)127;        // records
    const size_t offH = offR + (size_t)n * 16;                   // hist
    const size_t offC = offH + (size_t)NBIN2 * sizeof(int);      // cursor
    const size_t needSorted = offC + (size_t)NBIN2 * sizeof(int);

    if (ws_size >= needSorted) {
        char* ws = (char*)d_ws;
        f16x8* feats16 = (f16x8*)(ws + offF);
        f32x4* records = (f32x4*)(ws + offR);
        int*   hist    = (int*)(ws + offH);
        int*   cursor  = (int*)(ws + offC);

        hipMemsetAsync(hist, 0, (size_t)NBIN2 * sizeof(int), stream);

        convert_hist_kernel<<<(n8 + 255) / 256, 256, 0, stream>>>(
            (const f32x4*)feats, feats16, pos, hist, n8, n);

        scan_kernel<<<1, 1024, 0, stream>>>(hist, cursor);

        scatter_kernel<<<(n + 255) / 256, 256, 0, stream>>>(
            pos, cursor, records, n);

        const int nwg = (n + 31) / 32;
        trilerp_sorted_kernel<<<nwg, 256, 0, stream>>>(
            records, feats16, out4, n, nwg);
    } else if (ws_size >= featBytes) {
        f16x8* feats16 = (f16x8*)d_ws;
        convert_hist_kernel<<<(n8 + 255) / 256, 256, 0, stream>>>(
            (const f32x4*)feats, feats16, nullptr, nullptr, n8, 0);
        const long long total = (long long)n * 8;
        trilerp_f16_kernel<<<(int)((total + 255) / 256), 256, 0, stream>>>(
            pos, feats16, out4, n);
    } else {
        const long long total = (long long)n * 16;
        trilerp_f32_kernel<<<(int)((total + 255) / 256), 256, 0, stream>>>(
            pos, (const f32x4*)feats, out4, n);
    }
}